// Round 7
// baseline (249.684 us; speedup 1.0000x reference)
//
#include <hip/hip_runtime.h>
#include <hip/hip_bf16.h>

#define Bb 32
#define Ss 2048
#define Kk 1024   // 2*EH = 2*DH
#define Aa 512

#define BM 64                 // rows per block
#define BK 32                 // K per step
#define NT (Kk / BK)          // 32 K-steps
#define BBUF (Aa * BK * 2)    // 32 KB bf16 per B buffer

typedef __bf16 bf16x8 __attribute__((ext_vector_type(8)));
typedef float f32x4 __attribute__((ext_vector_type(4)));
typedef float f32x8 __attribute__((ext_vector_type(8)));

__device__ __forceinline__ unsigned short f2bf(float f) {
  unsigned u = __float_as_uint(f);
  u += 0x7FFFu + ((u >> 16) & 1u);   // RNE
  return (unsigned short)(u >> 16);
}

__device__ __forceinline__ float tanh_fast(float x) {
  float e = __expf(2.f * x);
  return (e - 1.f) / (e + 1.f);
}

__device__ __forceinline__ void gll16(const void* g, void* l) {
  __builtin_amdgcn_global_load_lds(
      (const __attribute__((address_space(1))) unsigned int*)g,
      (__attribute__((address_space(3))) unsigned int*)l, 16, 0, 0);
}

// ---- prep: WtT[t][g][a] = 16B chunk of bf16 W[t*32+g*8+j][a], j=0..7 ----
// Exact LDS image for K-step t: B LDS addr = g*8192 + a*16.
__global__ __launch_bounds__(256) void prep_wt(const float* __restrict__ W,
                                               unsigned short* __restrict__ WtT) {
  const int idx = blockIdx.x * 256 + threadIdx.x;   // 65536
  const int a = idx & 511;
  const int o = idx >> 9;            // octet 0..127
  const int t = o >> 2, g = o & 3;
  const int k0 = o * 8;
  unsigned short u[8];
#pragma unroll
  for (int j = 0; j < 8; ++j) u[j] = f2bf(W[(size_t)(k0 + j) * Aa + a]);
  uint4 pk;
  pk.x = (unsigned)u[0] | ((unsigned)u[1] << 16);
  pk.y = (unsigned)u[2] | ((unsigned)u[3] << 16);
  pk.z = (unsigned)u[4] | ((unsigned)u[5] << 16);
  pk.w = (unsigned)u[6] | ((unsigned)u[7] << 16);
  *(uint4*)((char*)WtT + (size_t)t * 32768 + g * 8192 + a * 16) = pk;
}

// ---- temp2 = [dh0|dh1] @ U ----
__global__ __launch_bounds__(256) void t2_partial(const float* __restrict__ dh,
                                                  const float* __restrict__ U,
                                                  float* __restrict__ part) {
  const int b = blockIdx.x, kc = blockIdx.y, t = threadIdx.x;  // (32, 8)
  __shared__ float sdh[128];
  if (t < 128) {
    int k = kc * 128 + t;
    sdh[t] = dh[(k >> 9) * (Bb * 512) + b * 512 + (k & 511)];
  }
  __syncthreads();
#pragma unroll
  for (int h = 0; h < 2; ++h) {
    const int a = h * 256 + t;
    float s = 0.f;
#pragma unroll 8
    for (int kk = 0; kk < 128; ++kk) s += sdh[kk] * U[(size_t)(kc * 128 + kk) * Aa + a];
    part[(size_t)(b * 8 + kc) * Aa + a] = s;
  }
}

__global__ __launch_bounds__(256) void t2_reduce(const float* __restrict__ part,
                                                 float* __restrict__ t2) {
  const int idx = blockIdx.x * 256 + threadIdx.x;  // 16384
  const int b = idx >> 9, a = idx & 511;
  float s = 0.f;
#pragma unroll
  for (int kc = 0; kc < 8; ++kc) s += part[(size_t)(b * 8 + kc) * Aa + a];
  t2[idx] = s;
}

// ---- main: scores = tanh(enc@W + t2) @ v ----
// Block = 256 thr (4 waves), tile 64x512, 64KB LDS -> 2 blocks/CU (two
// independent barrier domains). A (enc) loaded DIRECTLY global->VGPR,
// prefetched one iter ahead; only B staged in LDS (gll, dbuf, counted vmcnt).

// load A(TT) fragments into areg[S][0..7] (S is a LITERAL 0/1)
#define A_LOAD(S, TT)                                                           \
  if ((TT) < NT) {                                                              \
    const float* ap = encF + (TT) * BK + aoff;                                  \
    areg[S][0] = *(const float4*)(ap);                                          \
    areg[S][1] = *(const float4*)(ap + 4);                                      \
    areg[S][2] = *(const float4*)(ap + 16384);                                  \
    areg[S][3] = *(const float4*)(ap + 16388);                                  \
    areg[S][4] = *(const float4*)(ap + 32768);                                  \
    areg[S][5] = *(const float4*)(ap + 32772);                                  \
    areg[S][6] = *(const float4*)(ap + 49152);                                  \
    areg[S][7] = *(const float4*)(ap + 49156);                                  \
  }

// one K-step. FIFO at the wait (strict issue order):
//   ... gllB(T+1):8 | A(T+1):8, gllB(T+2):8   -> vmcnt(16) retires gllB(T+1).
#define ITER(curB, CUR, NXT, T, X)                                              \
  {                                                                             \
    bf16x8 af[4];                                                               \
    _Pragma("unroll")                                                           \
    for (int mi = 0; mi < 4; ++mi) {                                            \
      const f32x4 lo = *(const f32x4*)&areg[CUR][mi * 2];                       \
      const f32x4 hi = *(const f32x4*)&areg[CUR][mi * 2 + 1];                   \
      f32x8 w8 = {lo.x, lo.y, lo.z, lo.w, hi.x, hi.y, hi.z, hi.w};              \
      af[mi] = __builtin_convertvector(w8, bf16x8);                             \
    }                                                                           \
    A_LOAD(NXT, (T) + 1)                                                        \
    bf16x8 bfr[8];                                                              \
    _Pragma("unroll")                                                           \
    for (int ni = 0; ni < 8; ++ni) {                                            \
      const int a = wx * 128 + ni * 16 + (lane & 15);                           \
      bfr[ni] = *(const bf16x8*)((curB) + (lane >> 4) * 8192 + a * 16);         \
    }                                                                           \
    __builtin_amdgcn_s_setprio(1);                                              \
    _Pragma("unroll")                                                           \
    for (int mi = 0; mi < 4; ++mi)                                              \
      _Pragma("unroll")                                                         \
      for (int ni = 0; ni < 8; ++ni)                                            \
        acc[mi][ni] = __builtin_amdgcn_mfma_f32_16x16x32_bf16(af[mi], bfr[ni], acc[mi][ni], 0, 0, 0); \
    __builtin_amdgcn_s_setprio(0);                                              \
    __builtin_amdgcn_sched_barrier(0);                                          \
    __builtin_amdgcn_s_barrier();   /* all waves done reading curB */           \
    if ((T) + 2 < NT) {                                                         \
      const char* wb = wtB + (size_t)((T) + 2) * 32768;                         \
      gll16(wb + b_off0, (curB) + b_off0);                                      \
      gll16(wb + b_off1, (curB) + b_off1);                                      \
      gll16(wb + b_off2, (curB) + b_off2);                                      \
      gll16(wb + b_off3, (curB) + b_off3);                                      \
      gll16(wb + b_off4, (curB) + b_off4);                                      \
      gll16(wb + b_off5, (curB) + b_off5);                                      \
      gll16(wb + b_off6, (curB) + b_off6);                                      \
      gll16(wb + b_off7, (curB) + b_off7);                                      \
    }                                                                           \
    asm volatile("s_waitcnt vmcnt(" #X ")" ::: "memory");                       \
    __builtin_amdgcn_sched_barrier(0);                                          \
    __builtin_amdgcn_s_barrier();   /* B(T+1) published */                      \
  }

__global__ __launch_bounds__(256, 2) void score_gemm(const float* __restrict__ enc,
                                                     const unsigned short* __restrict__ WtT,
                                                     const float* __restrict__ t2,
                                                     const float* __restrict__ v,
                                                     float* __restrict__ score) {
  __shared__ __align__(16) char lds[2 * BBUF];   // 64 KB -> 2 blocks/CU
  char* sB0 = lds;
  char* sB1 = lds + BBUF;

  const int blk = blockIdx.x;               // 1024 blocks
  const int b = blk >> 5, sc = blk & 31;
  const float* encF = enc + (size_t)(b * Ss + sc * BM) * Kk;
  const char* wtB = (const char*)WtT;

  const int tid = threadIdx.x;
  const int lane = tid & 63;
  const int wx = tid >> 6;                  // 4 waves, wave tile 64x128

  // A direct-load per-lane offset: row = (lane&15) (+16*mi), k = (lane>>4)*8
  const int aoff = (lane & 15) * Kk + (lane >> 4) * 8;

  // B gll offsets (linear image, pre-built by prep_wt): 8 chunks/thread
  const int b_off0 = tid * 16;
  const int b_off1 = (256 + tid) * 16;
  const int b_off2 = (512 + tid) * 16;
  const int b_off3 = (768 + tid) * 16;
  const int b_off4 = (1024 + tid) * 16;
  const int b_off5 = (1280 + tid) * 16;
  const int b_off6 = (1536 + tid) * 16;
  const int b_off7 = (1792 + tid) * 16;

  const f32x4 zero = {0.f, 0.f, 0.f, 0.f};
  f32x4 acc[4][8];
#pragma unroll
  for (int i = 0; i < 4; ++i)
#pragma unroll
    for (int j = 0; j < 8; ++j) acc[i][j] = zero;

  float4 areg[2][8];   // two A prefetch sets; all indices compile-time

  // ---- prologue: gllB(0), A(0), gllB(1); retire gllB(0); barrier ----
  {
    gll16(wtB + b_off0, sB0 + b_off0);
    gll16(wtB + b_off1, sB0 + b_off1);
    gll16(wtB + b_off2, sB0 + b_off2);
    gll16(wtB + b_off3, sB0 + b_off3);
    gll16(wtB + b_off4, sB0 + b_off4);
    gll16(wtB + b_off5, sB0 + b_off5);
    gll16(wtB + b_off6, sB0 + b_off6);
    gll16(wtB + b_off7, sB0 + b_off7);
    A_LOAD(0, 0)
    const char* wb1 = wtB + 32768;
    gll16(wb1 + b_off0, sB1 + b_off0);
    gll16(wb1 + b_off1, sB1 + b_off1);
    gll16(wb1 + b_off2, sB1 + b_off2);
    gll16(wb1 + b_off3, sB1 + b_off3);
    gll16(wb1 + b_off4, sB1 + b_off4);
    gll16(wb1 + b_off5, sB1 + b_off5);
    gll16(wb1 + b_off6, sB1 + b_off6);
    gll16(wb1 + b_off7, sB1 + b_off7);
    asm volatile("s_waitcnt vmcnt(16)" ::: "memory");   // B(0) landed
    __builtin_amdgcn_sched_barrier(0);
    __builtin_amdgcn_s_barrier();
  }

  // steady state: T = 0..29 (guards always true, vmcnt(16))
  for (int t = 0; t < 30; t += 2) {
    ITER(sB0, 0, 1, t, 16)
    ITER(sB1, 1, 0, t + 1, 16)
  }
  // tail: T=30 (no gll issue; retire gllB(31) -> vmcnt(8)), T=31 (drain)
  ITER(sB0, 0, 1, 30, 8)
  ITER(sB1, 1, 0, 31, 0)

  // ---- epilogue: score_row += tanh(acc + t2[col]) * v[col] ----
  float t2v[8], vv[8];
#pragma unroll
  for (int ni = 0; ni < 8; ++ni) {
    int c = wx * 128 + ni * 16 + (lane & 15);
    t2v[ni] = t2[b * Aa + c];
    vv[ni] = v[c];
  }
  float sp[4][4];
#pragma unroll
  for (int mi = 0; mi < 4; ++mi)
#pragma unroll
    for (int j = 0; j < 4; ++j) sp[mi][j] = 0.f;
#pragma unroll
  for (int mi = 0; mi < 4; ++mi)
#pragma unroll
    for (int ni = 0; ni < 8; ++ni)
#pragma unroll
      for (int j = 0; j < 4; ++j) {
        float x = acc[mi][ni][j] + t2v[ni];
        sp[mi][j] += vv[ni] * tanh_fast(x);
      }

  // C/D layout: col = lane&15, row = mi*16 + (lane>>4)*4 + j.
  float* sbuf = (float*)lds;   // 64 rows x 4 waves
#pragma unroll
  for (int mi = 0; mi < 4; ++mi)
#pragma unroll
    for (int j = 0; j < 4; ++j) {
      float s = sp[mi][j];
      s += __shfl_xor(s, 1);
      s += __shfl_xor(s, 2);
      s += __shfl_xor(s, 4);
      s += __shfl_xor(s, 8);
      if ((lane & 15) == 0) {
        int r = mi * 16 + ((lane >> 4) << 2) + j;
        sbuf[r * 4 + wx] = s;
      }
    }
  __syncthreads();
  if (tid < BM) {
    float s = sbuf[tid * 4] + sbuf[tid * 4 + 1] + sbuf[tid * 4 + 2] + sbuf[tid * 4 + 3];
    score[b * Ss + sc * BM + tid] = s;
  }
}

// ---- softmax over S, in place in d_out's attention region ----
__global__ __launch_bounds__(256) void softmax_k(float* __restrict__ aw) {
  const int b = blockIdx.x, t = threadIdx.x;
  __shared__ float red[8];
  float s[8];
  float m = -3.4e38f;
#pragma unroll
  for (int i = 0; i < 8; ++i) {
    s[i] = aw[b * Ss + t + i * 256];
    m = fmaxf(m, s[i]);
  }
#pragma unroll
  for (int off = 1; off < 64; off <<= 1) m = fmaxf(m, __shfl_xor(m, off));
  const int lane = t & 63, wv = t >> 6;
  if (lane == 0) red[wv] = m;
  __syncthreads();
  m = fmaxf(fmaxf(red[0], red[1]), fmaxf(red[2], red[3]));
  float e[8];
  float l = 0.f;
#pragma unroll
  for (int i = 0; i < 8; ++i) { e[i] = __expf(s[i] - m); l += e[i]; }
#pragma unroll
  for (int off = 1; off < 64; off <<= 1) l += __shfl_xor(l, off);
  if (lane == 0) red[4 + wv] = l;
  __syncthreads();
  l = red[4] + red[5] + red[6] + red[7];
  const float inv = 1.f / l;
#pragma unroll
  for (int i = 0; i < 8; ++i) aw[b * Ss + t + i * 256] = e[i] * inv;
}

// ---- context = sum_s aw[s] * enc[b,s,:] ----
__global__ __launch_bounds__(256) void ctx_partial(const float* __restrict__ enc,
                                                   const float* __restrict__ aw,
                                                   float* __restrict__ part) {
  const int b = blockIdx.x, ch = blockIdx.y, t = threadIdx.x;  // (32, 32)
  __shared__ float sw[64];
  const int s0 = ch * 64;
  if (t < 64) sw[t] = aw[b * Ss + s0 + t];
  __syncthreads();
  float ax = 0.f, ay = 0.f, az = 0.f, aww = 0.f;
  const float* ebase = enc + (size_t)(b * Ss + s0) * Kk + t * 4;
#pragma unroll 4
  for (int r = 0; r < 64; ++r) {
    const float4 ev = *(const float4*)(ebase + (size_t)r * Kk);
    const float w = sw[r];
    ax += w * ev.x; ay += w * ev.y; az += w * ev.z; aww += w * ev.w;
  }
  float4 o; o.x = ax; o.y = ay; o.z = az; o.w = aww;
  *(float4*)(part + (size_t)(b * 32 + ch) * Kk + t * 4) = o;
}

__global__ __launch_bounds__(256) void ctx_reduce(const float* __restrict__ part,
                                                  float* __restrict__ ctx) {
  const int idx = blockIdx.x * 256 + threadIdx.x;   // 32768
  const int b = idx >> 10, e = idx & 1023;
  float s = 0.f;
#pragma unroll
  for (int ch = 0; ch < 32; ++ch) s += part[(size_t)(b * 32 + ch) * Kk + e];
  ctx[idx] = s;
}

extern "C" void kernel_launch(void* const* d_in, const int* in_sizes, int n_in,
                              void* d_out, int out_size, void* d_ws, size_t ws_size,
                              hipStream_t stream) {
  const float* dh  = (const float*)d_in[0];   // (2, 32, 512)
  const float* enc = (const float*)d_in[1];   // (32, 2048, 1024)
  const float* W   = (const float*)d_in[2];   // (1024, 512)
  const float* U   = (const float*)d_in[3];   // (1024, 512)
  const float* v   = (const float*)d_in[4];   // (512, 1)

  float* out_ctx = (float*)d_out;             // (32, 1, 1024) = 32768
  float* out_aw  = (float*)d_out + 32768;     // (32, 2048)    = 65536

  char* ws = (char*)d_ws;
  unsigned short* WtT = (unsigned short*)ws;                // 1 MB (octet-major)
  float* t2p   = (float*)(ws + 1048576);                    // 512 KB
  float* t2    = (float*)(ws + 1048576 + 524288);           // 64 KB
  float* cpart = (float*)(ws + 1048576 + 524288 + 65536);   // 4 MB

  prep_wt<<<256, 256, 0, stream>>>(W, WtT);
  t2_partial<<<dim3(32, 8), 256, 0, stream>>>(dh, U, t2p);
  t2_reduce<<<64, 256, 0, stream>>>(t2p, t2);
  score_gemm<<<1024, 256, 0, stream>>>(enc, WtT, t2, v, out_aw);
  softmax_k<<<32, 256, 0, stream>>>(out_aw);
  ctx_partial<<<dim3(32, 32), 256, 0, stream>>>(enc, out_aw, cpart);
  ctx_reduce<<<128, 256, 0, stream>>>(cpart, out_ctx);
}

// Round 8
// 171.498 us; speedup vs baseline: 1.4559x; 1.4559x over previous
//
#include <hip/hip_runtime.h>
#include <hip/hip_bf16.h>

#define Bb 32
#define Ss 2048
#define Kk 1024   // 2*EH = 2*DH
#define Aa 512

#define BM 128
#define BK 32
#define NT (Kk / BK)          // 32 K-tiles
#define ABUF (BM * BK * 2)    // 8 KB bf16, layout [ks][row] 16B
#define BBUF (Aa * BK * 2)    // 32 KB bf16, octet-major

typedef __bf16 bf16x8 __attribute__((ext_vector_type(8)));
typedef float f32x4 __attribute__((ext_vector_type(4)));
typedef float f32x8 __attribute__((ext_vector_type(8)));

__device__ __forceinline__ unsigned short f2bf(float f) {
  unsigned u = __float_as_uint(f);
  u += 0x7FFFu + ((u >> 16) & 1u);   // RNE
  return (unsigned short)(u >> 16);
}

__device__ __forceinline__ float tanh_fast(float x) {
  float e = __expf(2.f * x);
  return (e - 1.f) / (e + 1.f);
}

__device__ __forceinline__ void gll16(const void* g, void* l) {
  __builtin_amdgcn_global_load_lds(
      (const __attribute__((address_space(1))) unsigned int*)g,
      (__attribute__((address_space(3))) unsigned int*)l, 16, 0, 0);
}

// ---- prep: WtT[t][g][a] = 16B chunk of bf16 W[t*32+g*8+j][a], j=0..7 ----
// Exact LDS image for K-tile t: B LDS addr = g*8192 + a*16.
__global__ __launch_bounds__(256) void prep_wt(const float* __restrict__ W,
                                               unsigned short* __restrict__ WtT) {
  const int idx = blockIdx.x * 256 + threadIdx.x;   // 65536
  const int a = idx & 511;
  const int o = idx >> 9;            // octet 0..127
  const int t = o >> 2, g = o & 3;
  const int k0 = o * 8;
  unsigned short u[8];
#pragma unroll
  for (int j = 0; j < 8; ++j) u[j] = f2bf(W[(size_t)(k0 + j) * Aa + a]);
  uint4 pk;
  pk.x = (unsigned)u[0] | ((unsigned)u[1] << 16);
  pk.y = (unsigned)u[2] | ((unsigned)u[3] << 16);
  pk.z = (unsigned)u[4] | ((unsigned)u[5] << 16);
  pk.w = (unsigned)u[6] | ((unsigned)u[7] << 16);
  *(uint4*)((char*)WtT + (size_t)t * 32768 + g * 8192 + a * 16) = pk;
}

// ---- temp2 = [dh0|dh1] @ U ----
__global__ __launch_bounds__(256) void t2_partial(const float* __restrict__ dh,
                                                  const float* __restrict__ U,
                                                  float* __restrict__ part) {
  const int b = blockIdx.x, kc = blockIdx.y, t = threadIdx.x;  // (32, 8)
  __shared__ float sdh[128];
  if (t < 128) {
    int k = kc * 128 + t;
    sdh[t] = dh[(k >> 9) * (Bb * 512) + b * 512 + (k & 511)];
  }
  __syncthreads();
#pragma unroll
  for (int h = 0; h < 2; ++h) {
    const int a = h * 256 + t;
    float s = 0.f;
#pragma unroll 8
    for (int kk = 0; kk < 128; ++kk) s += sdh[kk] * U[(size_t)(kc * 128 + kk) * Aa + a];
    part[(size_t)(b * 8 + kc) * Aa + a] = s;
  }
}

__global__ __launch_bounds__(256) void t2_reduce(const float* __restrict__ part,
                                                 float* __restrict__ t2) {
  const int idx = blockIdx.x * 256 + threadIdx.x;  // 16384
  const int b = idx >> 9, a = idx & 511;
  float s = 0.f;
#pragma unroll
  for (int kc = 0; kc < 8; ++kc) s += part[(size_t)(b * 8 + kc) * Aa + a];
  t2[idx] = s;
}

// ---- main: scores = tanh(enc@W + t2) @ v ----
// m201-style 4-phase-per-2-tiles schedule. 8 waves (2x4), wave 64x128,
// 80 KB LDS. B: gll from WtT image; A: reg-stage fp32->bf16, write-late.
// vmcnt(6) at P1/P2/P3, never 0 in the main loop.

#define ARD(buf, mi) (*(const bf16x8*)((buf) + (lane >> 4) * 2048 + \
                        (wy * 64 + (mi) * 16 + (lane & 15)) * 16))
#define BRD(buf, ni) (*(const bf16x8*)((buf) + (lane >> 4) * 8192 + \
                        (wx * 128 + (ni) * 16 + (lane & 15)) * 16))

#define BARSEQ                                                                  \
  __builtin_amdgcn_sched_barrier(0);                                            \
  __builtin_amdgcn_s_barrier();                                                 \
  asm volatile("s_waitcnt lgkmcnt(0)" ::: "memory");                            \
  __builtin_amdgcn_sched_barrier(0);

#define ENDBAR                                                                  \
  __builtin_amdgcn_sched_barrier(0);                                            \
  __builtin_amdgcn_s_barrier();

#define VM(N)                                                                   \
  asm volatile("s_waitcnt vmcnt(" #N ")" ::: "memory");                         \
  __builtin_amdgcn_sched_barrier(0);

#define DO_MFMA(a0_, a1_, M0, M1)                                               \
  __builtin_amdgcn_s_setprio(1);                                                \
  _Pragma("unroll")                                                             \
  for (int ni = 0; ni < 8; ++ni) {                                              \
    acc[M0][ni] = __builtin_amdgcn_mfma_f32_16x16x32_bf16(a0_, bfr[ni], acc[M0][ni], 0, 0, 0); \
    acc[M1][ni] = __builtin_amdgcn_mfma_f32_16x16x32_bf16(a1_, bfr[ni], acc[M1][ni], 0, 0, 0); \
  }                                                                             \
  __builtin_amdgcn_s_setprio(0);

#define CVT_WRITE(dst, r0, r1)                                                  \
  {                                                                             \
    f32x8 w8_ = {r0.x, r0.y, r0.z, r0.w, r1.x, r1.y, r1.z, r1.w};               \
    *(bf16x8*)((dst) + a_wb) = __builtin_convertvector(w8_, bf16x8);            \
  }

#define BGLL(TT, dstB)                                                          \
  {                                                                             \
    const char* wb_ = wtB + (size_t)(TT) * 32768;                               \
    gll16(wb_ + b_off0, (dstB) + b_off0);                                       \
    gll16(wb_ + b_off1, (dstB) + b_off1);                                       \
    gll16(wb_ + b_off2, (dstB) + b_off2);                                       \
    gll16(wb_ + b_off3, (dstB) + b_off3);                                       \
  }

// entry invariant: bufA0=A(T), bufB0=B(T) ready; A(T+1) in aO regs (in flight),
// B(T+1) gll in flight (4). FIFO oldest->newest: aO(T+1):2, Bg(T+1):4.
#define ITER(T)                                                                 \
  {                                                                             \
    bf16x8 bfr[8], fa0, fa1;                                                    \
    /* P0: tile T, mi01 */                                                      \
    fa0 = ARD(sA0, 0); fa1 = ARD(sA0, 1);                                       \
    _Pragma("unroll")                                                           \
    for (int ni = 0; ni < 8; ++ni) bfr[ni] = BRD(sB0, ni);                      \
    { const float* ap = aG + ((T) + 2) * BK;                                    \
      aE0 = *(const float4*)ap; aE1 = *(const float4*)(ap + 4); }               \
    BARSEQ; DO_MFMA(fa0, fa1, 0, 1); ENDBAR;                                    \
    /* P1: tile T, mi23 */                                                      \
    fa0 = ARD(sA0, 2); fa1 = ARD(sA0, 3);                                       \
    BGLL((T) + 2, sB0);                                                         \
    VM(6);            /* retire aO(T+1)+Bg(T+1) */                              \
    CVT_WRITE(sA1, aO0, aO1);   /* A(T+1) */                                    \
    BARSEQ; DO_MFMA(fa0, fa1, 2, 3); ENDBAR;                                    \
    /* P2: tile T+1, mi01 */                                                    \
    fa0 = ARD(sA1, 0); fa1 = ARD(sA1, 1);                                       \
    _Pragma("unroll")                                                           \
    for (int ni = 0; ni < 8; ++ni) bfr[ni] = BRD(sB1, ni);                      \
    { const float* ap = aG + ((T) + 3) * BK;                                    \
      aO0 = *(const float4*)ap; aO1 = *(const float4*)(ap + 4); }               \
    VM(6);            /* retire aE(T+2) */                                      \
    CVT_WRITE(sA0, aE0, aE1);   /* A(T+2) */                                    \
    BARSEQ; DO_MFMA(fa0, fa1, 0, 1); ENDBAR;                                    \
    /* P3: tile T+1, mi23 */                                                    \
    fa0 = ARD(sA1, 2); fa1 = ARD(sA1, 3);                                       \
    BGLL((T) + 3, sB1);                                                         \
    VM(6);            /* retire Bg(T+2) -> bufB0 ready for next P0 */           \
    BARSEQ; DO_MFMA(fa0, fa1, 2, 3); ENDBAR;                                    \
  }

#define ITER_TAIL()                                                             \
  {                                                                             \
    bf16x8 bfr[8], fa0, fa1;                                                    \
    fa0 = ARD(sA0, 0); fa1 = ARD(sA0, 1);                                       \
    _Pragma("unroll")                                                           \
    for (int ni = 0; ni < 8; ++ni) bfr[ni] = BRD(sB0, ni);                      \
    BARSEQ; DO_MFMA(fa0, fa1, 0, 1); ENDBAR;                                    \
    fa0 = ARD(sA0, 2); fa1 = ARD(sA0, 3);                                       \
    VM(0);            /* retire aO(31)+Bg(31) */                                \
    CVT_WRITE(sA1, aO0, aO1);   /* A(31) */                                     \
    BARSEQ; DO_MFMA(fa0, fa1, 2, 3); ENDBAR;                                    \
    fa0 = ARD(sA1, 0); fa1 = ARD(sA1, 1);                                       \
    _Pragma("unroll")                                                           \
    for (int ni = 0; ni < 8; ++ni) bfr[ni] = BRD(sB1, ni);                      \
    BARSEQ; DO_MFMA(fa0, fa1, 0, 1); ENDBAR;                                    \
    fa0 = ARD(sA1, 2); fa1 = ARD(sA1, 3);                                       \
    BARSEQ; DO_MFMA(fa0, fa1, 2, 3); ENDBAR;                                    \
  }

__global__ __launch_bounds__(512, 2) void score_gemm(const float* __restrict__ enc,
                                                     const unsigned short* __restrict__ WtT,
                                                     const float* __restrict__ t2,
                                                     const float* __restrict__ v,
                                                     float* __restrict__ score) {
  __shared__ __align__(16) char lds[2 * (ABUF + BBUF)];   // 80 KB
  char* sA0 = lds;
  char* sA1 = lds + ABUF;
  char* sB0 = lds + 2 * ABUF;
  char* sB1 = lds + 2 * ABUF + BBUF;

  const int blk = blockIdx.x;               // 512 blocks
  const int b = blk >> 4, sc = blk & 15;
  const float* encF = enc + (size_t)(b * Ss + sc * BM) * Kk;
  const char* wtB = (const char*)WtT;

  const int tid = threadIdx.x;
  const int lane = tid & 63;
  const int wid = tid >> 6;
  const int wy = wid >> 2, wx = wid & 3;    // 2 x 4 waves, wave tile 64x128

  // A stage: thread -> (row = tid>>2, ks = tid&3); 32B global -> 16B bf16 LDS
  const int a_row = tid >> 2;
  const int a_ks = tid & 3;
  const float* aG = encF + (size_t)a_row * Kk + a_ks * 8;
  const int a_wb = a_ks * 2048 + a_row * 16;

  // B gll offsets (linear image): 4 chunks/thread
  const int b_off0 = tid * 16;
  const int b_off1 = (512 + tid) * 16;
  const int b_off2 = (1024 + tid) * 16;
  const int b_off3 = (1536 + tid) * 16;

  const f32x4 zero = {0.f, 0.f, 0.f, 0.f};
  f32x4 acc[4][8];
#pragma unroll
  for (int i = 0; i < 4; ++i)
#pragma unroll
    for (int j = 0; j < 8; ++j) acc[i][j] = zero;

  float4 aE0, aE1, aO0, aO1;

  // ---- prologue: establish the entry invariant ----
  {
    { const float* ap = aG;      aE0 = *(const float4*)ap; aE1 = *(const float4*)(ap + 4); }
    BGLL(0, sB0);
    { const float* ap = aG + BK; aO0 = *(const float4*)ap; aO1 = *(const float4*)(ap + 4); }
    BGLL(1, sB1);
    VM(10);                        // retire aE (A0 regs)
    CVT_WRITE(sA0, aE0, aE1);      // A(0)
    VM(6);                         // retire Bg(0); leaves aO:2 + Bg(1):4
    asm volatile("s_waitcnt lgkmcnt(0)" ::: "memory");
    ENDBAR;
  }

  for (int t = 0; t < 30; t += 2) {
    ITER(t)
  }
  ITER_TAIL()

  // ---- epilogue: score_row += tanh(acc + t2[col]) * v[col] ----
  float t2v[8], vv[8];
#pragma unroll
  for (int ni = 0; ni < 8; ++ni) {
    int c = wx * 128 + ni * 16 + (lane & 15);
    t2v[ni] = t2[b * Aa + c];
    vv[ni] = v[c];
  }
  float sp[4][4];
#pragma unroll
  for (int mi = 0; mi < 4; ++mi)
#pragma unroll
    for (int j = 0; j < 4; ++j) sp[mi][j] = 0.f;
#pragma unroll
  for (int mi = 0; mi < 4; ++mi)
#pragma unroll
    for (int ni = 0; ni < 8; ++ni)
#pragma unroll
      for (int j = 0; j < 4; ++j) {
        float x = acc[mi][ni][j] + t2v[ni];
        sp[mi][j] += vv[ni] * tanh_fast(x);
      }

  // C/D layout: col = lane&15, row = (lane>>4)*4 + j. Reduce over 16 col-lanes.
  float* sbuf = (float*)lds;   // 2 KB, inside sA0 region (dead by now)
#pragma unroll
  for (int mi = 0; mi < 4; ++mi)
#pragma unroll
    for (int j = 0; j < 4; ++j) {
      float s = sp[mi][j];
      s += __shfl_xor(s, 1);
      s += __shfl_xor(s, 2);
      s += __shfl_xor(s, 4);
      s += __shfl_xor(s, 8);
      if ((lane & 15) == 0) {
        int r = wy * 64 + mi * 16 + ((lane >> 4) << 2) + j;
        sbuf[r * 4 + wx] = s;
      }
    }
  __syncthreads();
  if (tid < BM) {
    float s = sbuf[tid * 4] + sbuf[tid * 4 + 1] + sbuf[tid * 4 + 2] + sbuf[tid * 4 + 3];
    score[b * Ss + sc * BM + tid] = s;
  }
}

// ---- softmax over S, in place in d_out's attention region ----
__global__ __launch_bounds__(256) void softmax_k(float* __restrict__ aw) {
  const int b = blockIdx.x, t = threadIdx.x;
  __shared__ float red[8];
  float s[8];
  float m = -3.4e38f;
#pragma unroll
  for (int i = 0; i < 8; ++i) {
    s[i] = aw[b * Ss + t + i * 256];
    m = fmaxf(m, s[i]);
  }
#pragma unroll
  for (int off = 1; off < 64; off <<= 1) m = fmaxf(m, __shfl_xor(m, off));
  const int lane = t & 63, wv = t >> 6;
  if (lane == 0) red[wv] = m;
  __syncthreads();
  m = fmaxf(fmaxf(red[0], red[1]), fmaxf(red[2], red[3]));
  float e[8];
  float l = 0.f;
#pragma unroll
  for (int i = 0; i < 8; ++i) { e[i] = __expf(s[i] - m); l += e[i]; }
#pragma unroll
  for (int off = 1; off < 64; off <<= 1) l += __shfl_xor(l, off);
  if (lane == 0) red[4 + wv] = l;
  __syncthreads();
  l = red[4] + red[5] + red[6] + red[7];
  const float inv = 1.f / l;
#pragma unroll
  for (int i = 0; i < 8; ++i) aw[b * Ss + t + i * 256] = e[i] * inv;
}

// ---- context = sum_s aw[s] * enc[b,s,:] ----
__global__ __launch_bounds__(256) void ctx_partial(const float* __restrict__ enc,
                                                   const float* __restrict__ aw,
                                                   float* __restrict__ part) {
  const int b = blockIdx.x, ch = blockIdx.y, t = threadIdx.x;  // (32, 32)
  __shared__ float sw[64];
  const int s0 = ch * 64;
  if (t < 64) sw[t] = aw[b * Ss + s0 + t];
  __syncthreads();
  float ax = 0.f, ay = 0.f, az = 0.f, aww = 0.f;
  const float* ebase = enc + (size_t)(b * Ss + s0) * Kk + t * 4;
#pragma unroll 4
  for (int r = 0; r < 64; ++r) {
    const float4 ev = *(const float4*)(ebase + (size_t)r * Kk);
    const float w = sw[r];
    ax += w * ev.x; ay += w * ev.y; az += w * ev.z; aww += w * ev.w;
  }
  float4 o; o.x = ax; o.y = ay; o.z = az; o.w = aww;
  *(float4*)(part + (size_t)(b * 32 + ch) * Kk + t * 4) = o;
}

__global__ __launch_bounds__(256) void ctx_reduce(const float* __restrict__ part,
                                                  float* __restrict__ ctx) {
  const int idx = blockIdx.x * 256 + threadIdx.x;   // 32768
  const int b = idx >> 10, e = idx & 1023;
  float s = 0.f;
#pragma unroll
  for (int ch = 0; ch < 32; ++ch) s += part[(size_t)(b * 32 + ch) * Kk + e];
  ctx[idx] = s;
}

extern "C" void kernel_launch(void* const* d_in, const int* in_sizes, int n_in,
                              void* d_out, int out_size, void* d_ws, size_t ws_size,
                              hipStream_t stream) {
  const float* dh  = (const float*)d_in[0];   // (2, 32, 512)
  const float* enc = (const float*)d_in[1];   // (32, 2048, 1024)
  const float* W   = (const float*)d_in[2];   // (1024, 512)
  const float* U   = (const float*)d_in[3];   // (1024, 512)
  const float* v   = (const float*)d_in[4];   // (512, 1)

  float* out_ctx = (float*)d_out;             // (32, 1, 1024) = 32768
  float* out_aw  = (float*)d_out + 32768;     // (32, 2048)    = 65536

  char* ws = (char*)d_ws;
  unsigned short* WtT = (unsigned short*)ws;                // 1 MB (octet-major)
  float* t2p   = (float*)(ws + 1048576);                    // 512 KB
  float* t2    = (float*)(ws + 1048576 + 524288);           // 64 KB
  float* cpart = (float*)(ws + 1048576 + 524288 + 65536);   // 4 MB

  prep_wt<<<256, 256, 0, stream>>>(W, WtT);
  t2_partial<<<dim3(32, 8), 256, 0, stream>>>(dh, U, t2p);
  t2_reduce<<<64, 256, 0, stream>>>(t2p, t2);
  score_gemm<<<512, 512, 0, stream>>>(enc, WtT, t2, v, out_aw);
  softmax_k<<<32, 256, 0, stream>>>(out_aw);
  ctx_partial<<<dim3(32, 32), 256, 0, stream>>>(enc, out_aw, cpart);
  ctx_reduce<<<128, 256, 0, stream>>>(cpart, out_ctx);
}